// Round 13
// baseline (186.772 us; speedup 1.0000x reference)
//
#include <hip/hip_runtime.h>

typedef __attribute__((ext_vector_type(8))) short bf16x8;
typedef __attribute__((ext_vector_type(4))) float f32x4;
typedef __attribute__((ext_vector_type(2))) float f32x2;
typedef __attribute__((ext_vector_type(4))) uint u32x4;

#define CAP 128    // pcsr row capacity (max total degree ~57)
#define EB 4096    // edges per pass-A block
#define NBJ 320    // bucket stride (313 buckets used, dst>>6)
#define BSH 6      // bucket shift: 64 nodes per bucket

__device__ __forceinline__ ushort f2bf(float f) {
    union { float f; uint u; } c; c.f = f;
    uint u = c.u;
    u += 0x7fffu + ((u >> 16) & 1u);   // RNE
    return (ushort)(u >> 16);
}
__device__ __forceinline__ f32x2 up2(uint u) {
    union { uint u; float f; } lo, hi;
    lo.u = u << 16; hi.u = u & 0xffff0000u;
    f32x2 r; r.x = lo.f; r.y = hi.f; return r;
}
__device__ __forceinline__ void acc4(f32x2* a, uint4 v) {
    a[0] += up2(v.x); a[1] += up2(v.y); a[2] += up2(v.z); a[3] += up2(v.w);
}

// ---------------- pass A: LDS-binned edge bucketing (no global atomics) + conversions ----------
__global__ __launch_bounds__(256) void fill_cvtA(
        const int* __restrict__ src, const int* __restrict__ dst,
        uint* __restrict__ region, ushort* __restrict__ cntA, int E, int nAB,
        const float* __restrict__ x, ushort* __restrict__ xb, int n4,
        const float* __restrict__ W1, ushort* __restrict__ W1T,
        const float* __restrict__ W2, ushort* __restrict__ W2T,
        const float* __restrict__ W3, ushort* __restrict__ W3T,
        const float* __restrict__ W4, ushort* __restrict__ W4T) {
    if ((int)blockIdx.x < nAB) {
        __shared__ uint lcnt[NBJ];
        int tid = threadIdx.x;
        for (int i = tid; i < NBJ; i += 256) lcnt[i] = 0;
        __syncthreads();
        int b = blockIdx.x;
        int e0 = b * EB;
        int eend = e0 + EB < E ? e0 + EB : E;
        for (int e = e0 + tid; e < eend; e += 256) {
            uint d = (uint)dst[e];
            uint s = (uint)src[e];
            uint j = d >> BSH;
            uint pos = atomicAdd(&lcnt[j], 1u);
            __builtin_nontemporal_store((d << 16) | s,
                                        &region[(((uint)b * NBJ + j) << 6) + pos]);
        }
        __syncthreads();
        for (int i = tid; i < NBJ; i += 256) cntA[(uint)b * NBJ + i] = (ushort)lcnt[i];
        return;
    }
    // conversion section: grid-stride over all items from a fixed block budget
    int total = n4 + 196608;
    int stride = ((int)gridDim.x - nAB) * 256;
    for (int idx = ((int)blockIdx.x - nAB) * 256 + (int)threadIdx.x; idx < total; idx += stride) {
        if (idx < n4) {
            float4 v = *(const float4*)&x[(size_t)idx * 4];
            ushort4 o; o.x = f2bf(v.x); o.y = f2bf(v.y); o.z = f2bf(v.z); o.w = f2bf(v.w);
            *(ushort4*)&xb[(size_t)idx * 4] = o;
            continue;
        }
        int i = idx - n4;
        if (i < 32768) {                       // W1: K=128 N=256 Npad=256
            int n = i & 255, k = i >> 8;
            W1T[n * 128 + k] = f2bf(W1[k * 256 + n]);
        } else if (i < 32768 + 65536) {        // W2
            int j = i - 32768; int n = j & 255, k = j >> 8;
            W2T[n * 256 + k] = f2bf(W2[k * 256 + n]);
        } else if (i < 32768 + 131072) {       // W3
            int j = i - 98304; int n = j & 255, k = j >> 8;
            W3T[n * 256 + k] = f2bf(W3[k * 256 + n]);
        } else if (i < 32768 + 131072 + 32768) { // W4: K=256 N=40 Npad=128
            int j = i - 163840; int n = j & 127, k = j >> 7;
            W4T[n * 256 + k] = f2bf(n < 40 ? W4[k * 40 + n] : 0.f);
        }
    }
}

// ---------------- pass B: per-bucket scatter into pcsr + degree write (LDS atomics only) -------
__global__ __launch_bounds__(256) void buildB(
        const uint* __restrict__ region, const ushort* __restrict__ cntA,
        int* __restrict__ cnt, ushort* __restrict__ pcsr, int N, int nAB) {
    __shared__ uint lcnt[64];
    __shared__ ushort ca[NBJ];
    int j = blockIdx.x;
    int tid = threadIdx.x;
    if (tid < 64) lcnt[tid] = 0;
    for (int b = tid; b < nAB; b += 256) ca[b] = cntA[(uint)b * NBJ + j];
    __syncthreads();
    int sub = tid >> 6;     // 4 concurrent sub-segments
    int i = tid & 63;
    int nbb = (nAB + 3) >> 2;
    for (int bb = 0; bb < nbb; ++bb) {
        int b = bb * 4 + sub;
        if (b < nAB && i < (int)ca[b]) {
            uint ev = region[(((uint)b * NBJ + j) << 6) + i];
            uint d = ev >> 16;
            uint pos = atomicAdd(&lcnt[d & 63], 1u);
            pcsr[((size_t)d << 7) + pos] = (ushort)(ev & 0xffffu);
        }
    }
    __syncthreads();
    int node = (j << BSH) + tid;
    if (tid < 64 && node < N) cnt[node] = (int)lcnt[tid];
}

// ---------------- XCD-chunked gather: h[n] = x[n] + sum_{src->n} x[src] (bf16) ----------------
// grid-stride virtual blocks; nt-store of h keeps the XCD's L2 owned by the read slice.
template <int D>
__global__ __launch_bounds__(256) void gather_chunk(
        const ushort* __restrict__ xb, const int* __restrict__ cnt,
        const ushort* __restrict__ pcsr, ushort* __restrict__ h, int N, int nVB) {
    constexpr int CF = D / 4;               // feats per chunk: 64 or 32
    constexpr int LPN = CF / 8;             // lanes per node: 8 or 4
    constexpr int NPB = 256 / LPN;          // nodes per block: 32 or 64
    constexpr int RS = (D == 256) ? 9 : 8;  // log2(row bytes)
    const char* xc = (const char*)xb;
    char* hc = (char*)h;
    int t = threadIdx.x;
    int l = t & (LPN - 1);
    for (int vb = blockIdx.x; vb < nVB; vb += gridDim.x) {
        int chunk = vb & 3;
        int node = (vb >> 2) * NPB + (t / LPN);
        if (node >= N) continue;
        uint fo2 = (uint)chunk * (CF * 2) + (uint)l * 16;
        int deg = cnt[node];
        const ushort* crow = pcsr + ((size_t)node << 7);
        uint selfoff = ((uint)node << RS) + fo2;

        f32x2 a[4], b[4] = {}, c[4] = {}, d[4] = {};
        {
            uint4 sv = *(const uint4*)(xc + selfoff);
            a[0] = up2(sv.x); a[1] = up2(sv.y); a[2] = up2(sv.z); a[3] = up2(sv.w);
        }
        int e = 0;
        for (; e + 4 <= deg; e += 4) {
            uint s0 = crow[e], s1 = crow[e + 1], s2 = crow[e + 2], s3 = crow[e + 3];
            uint4 v0 = *(const uint4*)(xc + (s0 << RS) + fo2);
            uint4 v1 = *(const uint4*)(xc + (s1 << RS) + fo2);
            uint4 v2 = *(const uint4*)(xc + (s2 << RS) + fo2);
            uint4 v3 = *(const uint4*)(xc + (s3 << RS) + fo2);
            acc4(a, v0); acc4(b, v1); acc4(c, v2); acc4(d, v3);
        }
        for (; e < deg; ++e) {
            uint s = crow[e];
            uint4 v = *(const uint4*)(xc + (s << RS) + fo2);
            acc4(a, v);
        }
        #pragma unroll
        for (int i = 0; i < 4; ++i) a[i] += (b[i] + c[i]) + d[i];
        u32x4 o;
        o.x = (uint)f2bf(a[0].x) | ((uint)f2bf(a[0].y) << 16);
        o.y = (uint)f2bf(a[1].x) | ((uint)f2bf(a[1].y) << 16);
        o.z = (uint)f2bf(a[2].x) | ((uint)f2bf(a[2].y) << 16);
        o.w = (uint)f2bf(a[3].x) | ((uint)f2bf(a[3].y) << 16);
        __builtin_nontemporal_store(o, (u32x4*)(hc + selfoff));
    }
}

// ---------------- final gather: out[n][f] = y[n][f] + sum y[src][f] + b[f], f<40 ----------------
__global__ __launch_bounds__(256) void gather_out_kernel(
        const ushort* __restrict__ y, const int* __restrict__ cnt,
        const ushort* __restrict__ pcsr, const float* __restrict__ b,
        float* __restrict__ out, int N, int nVB) {
    const char* yc = (const char*)y;
    int l = threadIdx.x & 7;
    uint fo2 = (uint)l * 16;   // byte offset within 128B row
    for (int vb = blockIdx.x; vb < nVB; vb += gridDim.x) {
        int node = vb * 32 + ((int)threadIdx.x >> 3);
        if (node >= N) continue;
        int deg = cnt[node];
        const ushort* crow = pcsr + ((size_t)node << 7);

        f32x2 a[4], bb[4] = {}, cc[4] = {}, dd[4] = {};
        {
            uint4 sv = *(const uint4*)(yc + ((uint)node << 7) + fo2);
            a[0] = up2(sv.x); a[1] = up2(sv.y); a[2] = up2(sv.z); a[3] = up2(sv.w);
        }
        int e = 0;
        for (; e + 4 <= deg; e += 4) {
            uint s0 = crow[e], s1 = crow[e + 1], s2 = crow[e + 2], s3 = crow[e + 3];
            uint4 v0 = *(const uint4*)(yc + (s0 << 7) + fo2);
            uint4 v1 = *(const uint4*)(yc + (s1 << 7) + fo2);
            uint4 v2 = *(const uint4*)(yc + (s2 << 7) + fo2);
            uint4 v3 = *(const uint4*)(yc + (s3 << 7) + fo2);
            acc4(a, v0); acc4(bb, v1); acc4(cc, v2); acc4(dd, v3);
        }
        for (; e < deg; ++e) {
            uint s = crow[e];
            uint4 v = *(const uint4*)(yc + (s << 7) + fo2);
            acc4(a, v);
        }
        #pragma unroll
        for (int i = 0; i < 4; ++i) a[i] += (bb[i] + cc[i]) + dd[i];

        if (l < 5) {   // feats l*8 .. l*8+7, only f<40 stored
            int f = l * 8;
            f32x4 o0, o1;
            o0.x = a[0].x + b[f + 0]; o0.y = a[0].y + b[f + 1];
            o0.z = a[1].x + b[f + 2]; o0.w = a[1].y + b[f + 3];
            o1.x = a[2].x + b[f + 4]; o1.y = a[2].y + b[f + 5];
            o1.z = a[3].x + b[f + 6]; o1.w = a[3].y + b[f + 7];
            __builtin_nontemporal_store(o0, (f32x4*)&out[(size_t)node * 40 + f]);
            __builtin_nontemporal_store(o1, (f32x4*)&out[(size_t)node * 40 + f + 4]);
        }
    }
}

// ---------------- MFMA bf16 GEMM: C = [relu](A @ B + bias) ----------------
#define GBM 64
#define GBN 128
#define GBK 64
#define LDT 72   // padded LDS row stride (shorts): 144B -> 2-way bank aliasing (free)

template <bool OUTF32, bool RELU>
__global__ __launch_bounds__(256) void mfma_gemm(
        const ushort* __restrict__ A, const ushort* __restrict__ BT,
        const float* __restrict__ bias, void* __restrict__ Cout,
        int M, int Ncols, int K, int Cld) {
    __shared__ __align__(16) ushort As[GBM * LDT];
    __shared__ __align__(16) ushort Bs[GBN * LDT];
    int tid = threadIdx.x;
    int lane = tid & 63;
    int wave = tid >> 6;
    int row0 = blockIdx.x * GBM;
    int col0 = blockIdx.y * GBN;
    int wr = (wave >> 1) * 32;   // wave row offset: 0 or 32
    int wc = (wave & 1) * 64;    // wave col offset: 0 or 64
    int sr = tid >> 3;           // staging row 0..31
    int sc = (tid & 7) * 8;      // staging col chunk (8 shorts = 16B)
    int rr = lane & 15;
    int kq = (lane >> 4) * 8;
    f32x4 acc[2][4] = {};

    for (int k0 = 0; k0 < K; k0 += GBK) {
        int4 a0 = *(const int4*)&A[(size_t)(row0 + sr) * K + k0 + sc];
        int4 a1 = *(const int4*)&A[(size_t)(row0 + sr + 32) * K + k0 + sc];
        int4 b0 = *(const int4*)&BT[(size_t)(col0 + sr) * K + k0 + sc];
        int4 b1 = *(const int4*)&BT[(size_t)(col0 + sr + 32) * K + k0 + sc];
        int4 b2 = *(const int4*)&BT[(size_t)(col0 + sr + 64) * K + k0 + sc];
        int4 b3 = *(const int4*)&BT[(size_t)(col0 + sr + 96) * K + k0 + sc];
        __syncthreads();
        *(int4*)&As[sr * LDT + sc] = a0;
        *(int4*)&As[(sr + 32) * LDT + sc] = a1;
        *(int4*)&Bs[sr * LDT + sc] = b0;
        *(int4*)&Bs[(sr + 32) * LDT + sc] = b1;
        *(int4*)&Bs[(sr + 64) * LDT + sc] = b2;
        *(int4*)&Bs[(sr + 96) * LDT + sc] = b3;
        __syncthreads();
        #pragma unroll
        for (int kk = 0; kk < 2; ++kk) {
            int kof = kk * 32 + kq;
            bf16x8 af[2], bfr[4];
            #pragma unroll
            for (int i = 0; i < 2; ++i)
                af[i] = *(const bf16x8*)&As[(wr + i * 16 + rr) * LDT + kof];
            #pragma unroll
            for (int j = 0; j < 4; ++j)
                bfr[j] = *(const bf16x8*)&Bs[(wc + j * 16 + rr) * LDT + kof];
            #pragma unroll
            for (int i = 0; i < 2; ++i)
                #pragma unroll
                for (int j = 0; j < 4; ++j)
                    acc[i][j] = __builtin_amdgcn_mfma_f32_16x16x32_bf16(af[i], bfr[j], acc[i][j], 0, 0, 0);
        }
    }

    int rq = (lane >> 4) * 4;
    #pragma unroll
    for (int j = 0; j < 4; ++j) {
        int col = col0 + wc + j * 16 + rr;
        if (col >= Ncols) continue;
        float bv = bias ? bias[col] : 0.f;
        #pragma unroll
        for (int i = 0; i < 2; ++i) {
            #pragma unroll
            for (int r = 0; r < 4; ++r) {
                int row = row0 + wr + i * 16 + rq + r;
                if (row >= M) continue;
                float v = acc[i][j][r] + bv;
                if (RELU) v = fmaxf(v, 0.f);
                if (OUTF32) __builtin_nontemporal_store(v, &((float*)Cout)[(size_t)row * Cld + col]);
                else        __builtin_nontemporal_store(f2bf(v), &((ushort*)Cout)[(size_t)row * Cld + col]);
            }
        }
    }
}

// ---------------- launch ----------------
static inline size_t al256(size_t x) { return (x + 255) & ~(size_t)255; }

extern "C" void kernel_launch(void* const* d_in, const int* in_sizes, int n_in,
                              void* d_out, int out_size, void* d_ws, size_t ws_size,
                              hipStream_t stream) {
    const float* x  = (const float*)d_in[0];
    const int*   ei = (const int*)d_in[1];
    const float* W1 = (const float*)d_in[2];
    const float* b1 = (const float*)d_in[3];
    const float* W2 = (const float*)d_in[4];
    const float* b2 = (const float*)d_in[5];
    const float* W3 = (const float*)d_in[6];
    const float* b3 = (const float*)d_in[7];
    const float* W4 = (const float*)d_in[8];
    const float* b4 = (const float*)d_in[9];
    float* out = (float*)d_out;

    int N = in_sizes[0] / 128;   // 20000
    int E = in_sizes[1] / 2;     // 640000
    const int* src = ei;
    const int* dst = ei + E;
    int Mpad = ((N + 127) / 128) * 128;
    int nAB = (E + EB - 1) / EB;          // 157 pass-A edge blocks
    int NB  = (N + 63) >> BSH;            // 313 buckets

    char* ws = (char*)d_ws;
    int* cnt       = (int*)ws;                       // N degrees
    ushort* pcsr   = (ushort*)(cnt + N);             // N*CAP
    ushort* cntA   = pcsr + (size_t)N * CAP;         // nAB*NBJ sub-counts
    uint* region   = (uint*)(cntA + (size_t)nAB * NBJ);  // nAB*NBJ*64 packed edges
    size_t off = al256((size_t)N * 4 + (size_t)N * CAP * 2 +
                       (size_t)nAB * NBJ * 2 + (size_t)nAB * NBJ * 64 * 4);
    ushort* xb   = (ushort*)(ws + off); off += al256((size_t)N * 128 * 2);
    ushort* bufH = (ushort*)(ws + off); off += al256((size_t)Mpad * 256 * 2);
    ushort* bufA = (ushort*)(ws + off); off += al256((size_t)Mpad * 256 * 2);
    ushort* bufB = (ushort*)(ws + off); off += al256((size_t)Mpad * 256 * 2);
    ushort* bufY = (ushort*)(ws + off); off += al256((size_t)Mpad * 64 * 2);   // bf16, 64-col rows
    ushort* W1T  = (ushort*)(ws + off); off += al256((size_t)256 * 128 * 2);
    ushort* W2T  = (ushort*)(ws + off); off += al256((size_t)256 * 256 * 2);
    ushort* W3T  = (ushort*)(ws + off); off += al256((size_t)256 * 256 * 2);
    ushort* W4T  = (ushort*)(ws + off); off += al256((size_t)128 * 256 * 2);

    // pass A: edge bucketing (LDS atomics) + all conversions, one dispatch
    int n4 = N * 128 / 4;
    fill_cvtA<<<nAB + 512, 256, 0, stream>>>(src, dst, region, cntA, E, nAB, x, xb, n4,
                                             W1, W1T, W2, W2T, W3, W3T, W4, W4T);
    // pass B: bucket -> pcsr + degrees (LDS atomics, block-local writes)
    buildB<<<NB, 256, 0, stream>>>(region, cntA, cnt, pcsr, N, nAB);

    int g1VB = ((N + 63) / 64) * 4;   // D=128 virtual blocks
    int g2VB = ((N + 31) / 32) * 4;   // D=256 virtual blocks
    int goVB = (N + 31) / 32;
    dim3 gemmGrid(Mpad / GBM, 2);
    dim3 gemmGrid4(Mpad / GBM, 1);

    // L1
    gather_chunk<128><<<1024, 256, 0, stream>>>(xb, cnt, pcsr, bufH, N, g1VB);
    mfma_gemm<false, true><<<gemmGrid, 256, 0, stream>>>(bufH, W1T, b1, bufA, N, 256, 128, 256);
    // L2
    gather_chunk<256><<<2048, 256, 0, stream>>>(bufA, cnt, pcsr, bufH, N, g2VB);
    mfma_gemm<false, true><<<gemmGrid, 256, 0, stream>>>(bufH, W2T, b2, bufB, N, 256, 256, 256);
    // L3
    gather_chunk<256><<<2048, 256, 0, stream>>>(bufB, cnt, pcsr, bufH, N, g2VB);
    mfma_gemm<false, true><<<gemmGrid, 256, 0, stream>>>(bufH, W3T, b3, bufA, N, 256, 256, 256);
    // L4: y4 = z3 @ W4 (bf16, 64-col padded; cols 40..63 exactly 0 via zero W4T rows)
    mfma_gemm<false, false><<<gemmGrid4, 256, 0, stream>>>(bufA, W4T, nullptr, bufY, N, 64, 256, 64);
    // out = y4 + agg(y4) + b4  (agg commutes with linear map)
    gather_out_kernel<<<512, 256, 0, stream>>>(bufY, cnt, pcsr, b4, out, N, goVB);
}

// Round 14
// 156.040 us; speedup vs baseline: 1.1969x; 1.1969x over previous
//
#include <hip/hip_runtime.h>

typedef __attribute__((ext_vector_type(8))) short bf16x8;
typedef __attribute__((ext_vector_type(4))) float f32x4;
typedef __attribute__((ext_vector_type(2))) float f32x2;

#define CAP 128    // pcsr row capacity (max total degree ~57)
#define EB 4096    // edges per pass-A block
#define NBJ 320    // bucket stride (313 buckets used, dst>>6)
#define BSH 6      // bucket shift: 64 nodes per bucket

__device__ __forceinline__ ushort f2bf(float f) {
    union { float f; uint u; } c; c.f = f;
    uint u = c.u;
    u += 0x7fffu + ((u >> 16) & 1u);   // RNE
    return (ushort)(u >> 16);
}
__device__ __forceinline__ f32x2 up2(uint u) {
    union { uint u; float f; } lo, hi;
    lo.u = u << 16; hi.u = u & 0xffff0000u;
    f32x2 r; r.x = lo.f; r.y = hi.f; return r;
}
__device__ __forceinline__ void acc4(f32x2* a, uint4 v) {
    a[0] += up2(v.x); a[1] += up2(v.y); a[2] += up2(v.z); a[3] += up2(v.w);
}

// ---------------- pass A: LDS-binned edge bucketing (no global atomics) + conversions ----------
__global__ __launch_bounds__(256) void fill_cvtA(
        const int* __restrict__ src, const int* __restrict__ dst,
        uint* __restrict__ region, ushort* __restrict__ cntA, int E, int nAB,
        const float* __restrict__ x, ushort* __restrict__ xb, int n4,
        const float* __restrict__ W1, ushort* __restrict__ W1T,
        const float* __restrict__ W2, ushort* __restrict__ W2T,
        const float* __restrict__ W3, ushort* __restrict__ W3T,
        const float* __restrict__ W4, ushort* __restrict__ W4T) {
    if ((int)blockIdx.x < nAB) {
        __shared__ uint lcnt[NBJ];
        int tid = threadIdx.x;
        for (int i = tid; i < NBJ; i += 256) lcnt[i] = 0;
        __syncthreads();
        int b = blockIdx.x;
        int e0 = b * EB;
        int eend = e0 + EB < E ? e0 + EB : E;
        for (int e = e0 + tid; e < eend; e += 256) {
            uint d = (uint)dst[e];
            uint s = (uint)src[e];
            uint j = d >> BSH;
            uint pos = atomicAdd(&lcnt[j], 1u);
            region[(((uint)b * NBJ + j) << 6) + pos] = (d << 16) | s;
        }
        __syncthreads();
        for (int i = tid; i < NBJ; i += 256) cntA[(uint)b * NBJ + i] = (ushort)lcnt[i];
        return;
    }
    int idx = ((int)blockIdx.x - nAB) * 256 + threadIdx.x;
    if (idx < n4) {
        float4 v = *(const float4*)&x[(size_t)idx * 4];
        ushort4 o; o.x = f2bf(v.x); o.y = f2bf(v.y); o.z = f2bf(v.z); o.w = f2bf(v.w);
        *(ushort4*)&xb[(size_t)idx * 4] = o;
        return;
    }
    int i = idx - n4;
    if (i < 32768) {                       // W1: K=128 N=256 Npad=256
        int n = i & 255, k = i >> 8;
        W1T[n * 128 + k] = f2bf(W1[k * 256 + n]);
    } else if (i < 32768 + 65536) {        // W2
        int j = i - 32768; int n = j & 255, k = j >> 8;
        W2T[n * 256 + k] = f2bf(W2[k * 256 + n]);
    } else if (i < 32768 + 131072) {       // W3
        int j = i - 98304; int n = j & 255, k = j >> 8;
        W3T[n * 256 + k] = f2bf(W3[k * 256 + n]);
    } else if (i < 32768 + 131072 + 32768) { // W4: K=256 N=40 Npad=128
        int j = i - 163840; int n = j & 127, k = j >> 7;
        W4T[n * 256 + k] = f2bf(n < 40 ? W4[k * 40 + n] : 0.f);
    }
}

// ---------------- pass B: per-bucket scatter into pcsr + degree write (LDS atomics only) -------
__global__ __launch_bounds__(256) void buildB(
        const uint* __restrict__ region, const ushort* __restrict__ cntA,
        int* __restrict__ cnt, ushort* __restrict__ pcsr, int N, int nAB) {
    __shared__ uint lcnt[64];
    __shared__ ushort ca[NBJ];
    int j = blockIdx.x;
    int tid = threadIdx.x;
    if (tid < 64) lcnt[tid] = 0;
    for (int b = tid; b < nAB; b += 256) ca[b] = cntA[(uint)b * NBJ + j];
    __syncthreads();
    int sub = tid >> 6;     // 4 concurrent sub-segments
    int i = tid & 63;
    int nbb = (nAB + 3) >> 2;
    for (int bb = 0; bb < nbb; ++bb) {
        int b = bb * 4 + sub;
        if (b < nAB && i < (int)ca[b]) {
            uint ev = region[(((uint)b * NBJ + j) << 6) + i];
            uint d = ev >> 16;
            uint pos = atomicAdd(&lcnt[d & 63], 1u);
            pcsr[((size_t)d << 7) + pos] = (ushort)(ev & 0xffffu);
        }
    }
    __syncthreads();
    int node = (j << BSH) + tid;
    if (tid < 64 && node < N) cnt[node] = (int)lcnt[tid];
}

// ---------------- XCD-chunked gather: h[n] = x[n] + sum_{src->n} x[src] (bf16) ----------------
// chunk = blockIdx&3 (XCD L2 locality). uint4 (16B = 8 bf16) per lane, 8 loads in
// flight (2 rounds into 4 packed accumulator sets), f32x2 accumulators.
template <int D>
__global__ __launch_bounds__(256) void gather_chunk(
        const ushort* __restrict__ xb, const int* __restrict__ cnt,
        const ushort* __restrict__ pcsr, ushort* __restrict__ h, int N) {
    constexpr int CF = D / 4;               // feats per chunk: 64 or 32
    constexpr int LPN = CF / 8;             // lanes per node: 8 or 4
    constexpr int NPB = 256 / LPN;          // nodes per block: 32 or 64
    constexpr int RS = (D == 256) ? 9 : 8;  // log2(row bytes)
    int chunk = blockIdx.x & 3;
    int t = threadIdx.x;
    int node = (blockIdx.x >> 2) * NPB + (t / LPN);
    if (node >= N) return;
    int l = t & (LPN - 1);
    uint fo2 = (uint)chunk * (CF * 2) + (uint)l * 16;
    const char* xc = (const char*)xb;
    char* hc = (char*)h;
    int deg = cnt[node];
    const ushort* crow = pcsr + ((size_t)node << 7);
    uint selfoff = ((uint)node << RS) + fo2;

    f32x2 a[4], b[4] = {}, c[4] = {}, d[4] = {};
    {
        uint4 sv = *(const uint4*)(xc + selfoff);
        a[0] = up2(sv.x); a[1] = up2(sv.y); a[2] = up2(sv.z); a[3] = up2(sv.w);
    }
    int e = 0;
    for (; e + 8 <= deg; e += 8) {
        uint s0 = crow[e],     s1 = crow[e + 1], s2 = crow[e + 2], s3 = crow[e + 3];
        uint s4 = crow[e + 4], s5 = crow[e + 5], s6 = crow[e + 6], s7 = crow[e + 7];
        uint4 v0 = *(const uint4*)(xc + (s0 << RS) + fo2);
        uint4 v1 = *(const uint4*)(xc + (s1 << RS) + fo2);
        uint4 v2 = *(const uint4*)(xc + (s2 << RS) + fo2);
        uint4 v3 = *(const uint4*)(xc + (s3 << RS) + fo2);
        uint4 v4 = *(const uint4*)(xc + (s4 << RS) + fo2);
        uint4 v5 = *(const uint4*)(xc + (s5 << RS) + fo2);
        uint4 v6 = *(const uint4*)(xc + (s6 << RS) + fo2);
        uint4 v7 = *(const uint4*)(xc + (s7 << RS) + fo2);
        acc4(a, v0); acc4(b, v1); acc4(c, v2); acc4(d, v3);
        acc4(a, v4); acc4(b, v5); acc4(c, v6); acc4(d, v7);
    }
    for (; e + 4 <= deg; e += 4) {
        uint s0 = crow[e], s1 = crow[e + 1], s2 = crow[e + 2], s3 = crow[e + 3];
        uint4 v0 = *(const uint4*)(xc + (s0 << RS) + fo2);
        uint4 v1 = *(const uint4*)(xc + (s1 << RS) + fo2);
        uint4 v2 = *(const uint4*)(xc + (s2 << RS) + fo2);
        uint4 v3 = *(const uint4*)(xc + (s3 << RS) + fo2);
        acc4(a, v0); acc4(b, v1); acc4(c, v2); acc4(d, v3);
    }
    for (; e < deg; ++e) {
        uint s = crow[e];
        uint4 v = *(const uint4*)(xc + (s << RS) + fo2);
        acc4(a, v);
    }
    #pragma unroll
    for (int i = 0; i < 4; ++i) a[i] += (b[i] + c[i]) + d[i];
    uint4 o;
    o.x = (uint)f2bf(a[0].x) | ((uint)f2bf(a[0].y) << 16);
    o.y = (uint)f2bf(a[1].x) | ((uint)f2bf(a[1].y) << 16);
    o.z = (uint)f2bf(a[2].x) | ((uint)f2bf(a[2].y) << 16);
    o.w = (uint)f2bf(a[3].x) | ((uint)f2bf(a[3].y) << 16);
    *(uint4*)(hc + selfoff) = o;
}

// ---------------- final gather: out[n][f] = y[n][f] + sum y[src][f] + b[f], f<40 ----------------
// y: bf16 [Mpad][64] rows (128B, cols 40..63 exact zeros -> 2.56MB, L2-replicable).
__global__ __launch_bounds__(256) void gather_out_kernel(
        const ushort* __restrict__ y, const int* __restrict__ cnt,
        const ushort* __restrict__ pcsr, const float* __restrict__ b,
        float* __restrict__ out, int N) {
    int node = blockIdx.x * 32 + (threadIdx.x >> 3);
    if (node >= N) return;
    int l = threadIdx.x & 7;
    uint fo2 = (uint)l * 16;   // byte offset within 128B row
    const char* yc = (const char*)y;
    int deg = cnt[node];
    const ushort* crow = pcsr + ((size_t)node << 7);

    f32x2 a[4], bb[4] = {}, cc[4] = {}, dd[4] = {};
    {
        uint4 sv = *(const uint4*)(yc + ((uint)node << 7) + fo2);
        a[0] = up2(sv.x); a[1] = up2(sv.y); a[2] = up2(sv.z); a[3] = up2(sv.w);
    }
    int e = 0;
    for (; e + 4 <= deg; e += 4) {
        uint s0 = crow[e], s1 = crow[e + 1], s2 = crow[e + 2], s3 = crow[e + 3];
        uint4 v0 = *(const uint4*)(yc + (s0 << 7) + fo2);
        uint4 v1 = *(const uint4*)(yc + (s1 << 7) + fo2);
        uint4 v2 = *(const uint4*)(yc + (s2 << 7) + fo2);
        uint4 v3 = *(const uint4*)(yc + (s3 << 7) + fo2);
        acc4(a, v0); acc4(bb, v1); acc4(cc, v2); acc4(dd, v3);
    }
    for (; e < deg; ++e) {
        uint s = crow[e];
        uint4 v = *(const uint4*)(yc + (s << 7) + fo2);
        acc4(a, v);
    }
    #pragma unroll
    for (int i = 0; i < 4; ++i) a[i] += (bb[i] + cc[i]) + dd[i];

    if (l < 5) {   // feats l*8 .. l*8+7, only f<40 stored
        int f = l * 8;
        float4 o0 = make_float4(a[0].x + b[f + 0], a[0].y + b[f + 1],
                                a[1].x + b[f + 2], a[1].y + b[f + 3]);
        float4 o1 = make_float4(a[2].x + b[f + 4], a[2].y + b[f + 5],
                                a[3].x + b[f + 6], a[3].y + b[f + 7]);
        *(float4*)&out[(size_t)node * 40 + f] = o0;
        *(float4*)&out[(size_t)node * 40 + f + 4] = o1;
    }
}

// ---------------- MFMA bf16 GEMM: C = [relu](A @ B + bias) ----------------
#define GBM 64
#define GBN 128
#define GBK 64
#define LDT 72   // padded LDS row stride (shorts): 144B -> 2-way bank aliasing (free)

template <bool OUTF32, bool RELU>
__global__ __launch_bounds__(256) void mfma_gemm(
        const ushort* __restrict__ A, const ushort* __restrict__ BT,
        const float* __restrict__ bias, void* __restrict__ Cout,
        int M, int Ncols, int K, int Cld) {
    __shared__ __align__(16) ushort As[GBM * LDT];
    __shared__ __align__(16) ushort Bs[GBN * LDT];
    int tid = threadIdx.x;
    int lane = tid & 63;
    int wave = tid >> 6;
    int row0 = blockIdx.x * GBM;
    int col0 = blockIdx.y * GBN;
    int wr = (wave >> 1) * 32;   // wave row offset: 0 or 32
    int wc = (wave & 1) * 64;    // wave col offset: 0 or 64
    int sr = tid >> 3;           // staging row 0..31
    int sc = (tid & 7) * 8;      // staging col chunk (8 shorts = 16B)
    int rr = lane & 15;
    int kq = (lane >> 4) * 8;
    f32x4 acc[2][4] = {};

    for (int k0 = 0; k0 < K; k0 += GBK) {
        int4 a0 = *(const int4*)&A[(size_t)(row0 + sr) * K + k0 + sc];
        int4 a1 = *(const int4*)&A[(size_t)(row0 + sr + 32) * K + k0 + sc];
        int4 b0 = *(const int4*)&BT[(size_t)(col0 + sr) * K + k0 + sc];
        int4 b1 = *(const int4*)&BT[(size_t)(col0 + sr + 32) * K + k0 + sc];
        int4 b2 = *(const int4*)&BT[(size_t)(col0 + sr + 64) * K + k0 + sc];
        int4 b3 = *(const int4*)&BT[(size_t)(col0 + sr + 96) * K + k0 + sc];
        __syncthreads();
        *(int4*)&As[sr * LDT + sc] = a0;
        *(int4*)&As[(sr + 32) * LDT + sc] = a1;
        *(int4*)&Bs[sr * LDT + sc] = b0;
        *(int4*)&Bs[(sr + 32) * LDT + sc] = b1;
        *(int4*)&Bs[(sr + 64) * LDT + sc] = b2;
        *(int4*)&Bs[(sr + 96) * LDT + sc] = b3;
        __syncthreads();
        #pragma unroll
        for (int kk = 0; kk < 2; ++kk) {
            int kof = kk * 32 + kq;
            bf16x8 af[2], bfr[4];
            #pragma unroll
            for (int i = 0; i < 2; ++i)
                af[i] = *(const bf16x8*)&As[(wr + i * 16 + rr) * LDT + kof];
            #pragma unroll
            for (int j = 0; j < 4; ++j)
                bfr[j] = *(const bf16x8*)&Bs[(wc + j * 16 + rr) * LDT + kof];
            #pragma unroll
            for (int i = 0; i < 2; ++i)
                #pragma unroll
                for (int j = 0; j < 4; ++j)
                    acc[i][j] = __builtin_amdgcn_mfma_f32_16x16x32_bf16(af[i], bfr[j], acc[i][j], 0, 0, 0);
        }
    }

    int rq = (lane >> 4) * 4;
    #pragma unroll
    for (int j = 0; j < 4; ++j) {
        int col = col0 + wc + j * 16 + rr;
        if (col >= Ncols) continue;
        float bv = bias ? bias[col] : 0.f;
        #pragma unroll
        for (int i = 0; i < 2; ++i) {
            #pragma unroll
            for (int r = 0; r < 4; ++r) {
                int row = row0 + wr + i * 16 + rq + r;
                if (row >= M) continue;
                float v = acc[i][j][r] + bv;
                if (RELU) v = fmaxf(v, 0.f);
                if (OUTF32) ((float*)Cout)[(size_t)row * Cld + col] = v;
                else        ((ushort*)Cout)[(size_t)row * Cld + col] = f2bf(v);
            }
        }
    }
}

// ---------------- launch ----------------
static inline size_t al256(size_t x) { return (x + 255) & ~(size_t)255; }

extern "C" void kernel_launch(void* const* d_in, const int* in_sizes, int n_in,
                              void* d_out, int out_size, void* d_ws, size_t ws_size,
                              hipStream_t stream) {
    const float* x  = (const float*)d_in[0];
    const int*   ei = (const int*)d_in[1];
    const float* W1 = (const float*)d_in[2];
    const float* b1 = (const float*)d_in[3];
    const float* W2 = (const float*)d_in[4];
    const float* b2 = (const float*)d_in[5];
    const float* W3 = (const float*)d_in[6];
    const float* b3 = (const float*)d_in[7];
    const float* W4 = (const float*)d_in[8];
    const float* b4 = (const float*)d_in[9];
    float* out = (float*)d_out;

    int N = in_sizes[0] / 128;   // 20000
    int E = in_sizes[1] / 2;     // 640000
    const int* src = ei;
    const int* dst = ei + E;
    int Mpad = ((N + 127) / 128) * 128;
    int nAB = (E + EB - 1) / EB;          // 157 pass-A edge blocks
    int NB  = (N + 63) >> BSH;            // 313 buckets

    char* ws = (char*)d_ws;
    int* cnt       = (int*)ws;                       // N degrees
    ushort* pcsr   = (ushort*)(cnt + N);             // N*CAP
    ushort* cntA   = pcsr + (size_t)N * CAP;         // nAB*NBJ sub-counts
    uint* region   = (uint*)(cntA + (size_t)nAB * NBJ);  // nAB*NBJ*64 packed edges
    size_t off = al256((size_t)N * 4 + (size_t)N * CAP * 2 +
                       (size_t)nAB * NBJ * 2 + (size_t)nAB * NBJ * 64 * 4);
    ushort* xb   = (ushort*)(ws + off); off += al256((size_t)N * 128 * 2);
    ushort* bufH = (ushort*)(ws + off); off += al256((size_t)Mpad * 256 * 2);
    ushort* bufA = (ushort*)(ws + off); off += al256((size_t)Mpad * 256 * 2);
    ushort* bufB = (ushort*)(ws + off); off += al256((size_t)Mpad * 256 * 2);
    ushort* bufY = (ushort*)(ws + off); off += al256((size_t)Mpad * 64 * 2);   // bf16, 64-col rows
    ushort* W1T  = (ushort*)(ws + off); off += al256((size_t)256 * 128 * 2);
    ushort* W2T  = (ushort*)(ws + off); off += al256((size_t)256 * 256 * 2);
    ushort* W3T  = (ushort*)(ws + off); off += al256((size_t)256 * 256 * 2);
    ushort* W4T  = (ushort*)(ws + off); off += al256((size_t)128 * 256 * 2);

    // pass A: edge bucketing (LDS atomics) + all conversions, one dispatch
    int n4 = N * 128 / 4;
    int cvtBlocks = (n4 + 196608 + 255) / 256;
    fill_cvtA<<<nAB + cvtBlocks, 256, 0, stream>>>(src, dst, region, cntA, E, nAB, x, xb, n4,
                                                   W1, W1T, W2, W2T, W3, W3T, W4, W4T);
    // pass B: bucket -> pcsr + degrees (LDS atomics, block-local writes)
    buildB<<<NB, 256, 0, stream>>>(region, cntA, cnt, pcsr, N, nAB);

    int g1Blocks = ((N + 63) / 64) * 4;   // D=128: 64 nodes/block
    int g2Blocks = ((N + 31) / 32) * 4;   // D=256: 32 nodes/block
    dim3 gemmGrid(Mpad / GBM, 2);
    dim3 gemmGrid4(Mpad / GBM, 1);

    // L1
    gather_chunk<128><<<g1Blocks, 256, 0, stream>>>(xb, cnt, pcsr, bufH, N);
    mfma_gemm<false, true><<<gemmGrid, 256, 0, stream>>>(bufH, W1T, b1, bufA, N, 256, 128, 256);
    // L2
    gather_chunk<256><<<g2Blocks, 256, 0, stream>>>(bufA, cnt, pcsr, bufH, N);
    mfma_gemm<false, true><<<gemmGrid, 256, 0, stream>>>(bufH, W2T, b2, bufB, N, 256, 256, 256);
    // L3
    gather_chunk<256><<<g2Blocks, 256, 0, stream>>>(bufB, cnt, pcsr, bufH, N);
    mfma_gemm<false, true><<<gemmGrid, 256, 0, stream>>>(bufH, W3T, b3, bufA, N, 256, 256, 256);
    // L4: y4 = z3 @ W4 (bf16, 64-col padded; cols 40..63 exactly 0 via zero W4T rows)
    mfma_gemm<false, false><<<gemmGrid4, 256, 0, stream>>>(bufA, W4T, nullptr, bufY, N, 64, 256, 64);
    // out = y4 + agg(y4) + b4  (agg commutes with linear map)
    gather_out_kernel<<<(N + 31) / 32, 256, 0, stream>>>(bufY, cnt, pcsr, b4, out, N);
}